// Round 4
// baseline (98.322 us; speedup 1.0000x reference)
//
#include <hip/hip_runtime.h>
#include <hip/hip_fp16.h>

// ROI pooling: crop_and_resize (bilinear, 14x14) + 2x2 max pool -> (256,7,7,512) fp32
// feature_maps: (2,50,50,512) fp32 NHWC ; rois: (2,128,4) fp32
// reference permutes [1,0,3,2] -> y1=roi[1], x1=roi[0], y2=roi[3], x2=roi[2]
//
// R4: per-ROI separable staging. One block per (ROI, 128-ch slab); block walks
// iy=0..13 staging the two needed rows (x-window only) into a parity-indexed
// 2-slot LDS row cache (ys monotone -> each distinct row loaded exactly once),
// then all 14 ix samples read taps from LDS. Cuts global tap traffic from
// 205 MB (R3, per-sample fetch, ~2.4x redundant) to ~78 MB expected, and
// moves the 4-tap bilinear reads onto the LDS pipe.
// fp16 pre-pass retained (halves staged bytes; error << threshold).

constexpr int H = 50, W = 50, C = 512;
constexpr int POOLEDX = 7, CROP = 14;
constexpr int RPB = 128;
constexpr int PIX = POOLEDX * POOLEDX;     // 49
constexpr int NROI = 2 * RPB;              // 256
constexpr int NELEM = 2 * H * W * C;       // 2,560,000 floats
constexpr int SLABCH = 128;                // channels per slab
constexpr int NSLAB  = C / SLABCH;         // 4
constexpr int LSTR   = SLABCH + 8;         // 136 halves: pad to decorrelate LDS banks

// ---------- pre-pass: fm fp32 -> fp16 into workspace ----------
__global__ __launch_bounds__(256) void cvt_kernel(
    const float* __restrict__ in, __half* __restrict__ out)
{
    const int i = (blockIdx.x * 256 + threadIdx.x) * 8;
    const float4* in4 = reinterpret_cast<const float4*>(in + i);
    const float4 a = in4[0];
    const float4 b = in4[1];
    __half h[8];
    h[0]=__float2half(a.x); h[1]=__float2half(a.y); h[2]=__float2half(a.z); h[3]=__float2half(a.w);
    h[4]=__float2half(b.x); h[5]=__float2half(b.y); h[6]=__float2half(b.z); h[7]=__float2half(b.w);
    *reinterpret_cast<float4*>(out + i) = *reinterpret_cast<const float4*>(h);
}

// ---------- main: one block per (ROI, slab) ----------
__global__ __launch_bounds__(256) void roi_pool_kernel(
    const __half* __restrict__ fmh,
    const float* __restrict__ rois,
    float* __restrict__ out)
{
    __shared__ __half lds[2][W][LSTR];       // 2*50*136*2 B = 27,200 B

    const int hw   = blockIdx.x;             // 0..1023
    const int n    = hw >> 2;                // ROI id
    const int slab = hw & 3;
    const int bat  = n / RPB;
    const int t    = threadIdx.x;
    const int g    = t & 15;                 // 8-ch group within slab
    const int j    = t >> 4;                 // 0..15: ix lane / staging px lane

    const float rx1 = rois[n*4+0], ry1 = rois[n*4+1];
    const float rx2 = rois[n*4+2], ry2 = rois[n*4+3];
    const float ybase = ry1 * 49.0f, xbase = rx1 * 49.0f;
    const float ystep = ((ry2 - ry1) * 49.0f) / 13.0f;   // match ref op order
    const float xstep = ((rx2 - rx1) * 49.0f) / 13.0f;

    // x-window from endpoints (xs linear in ix => monotone either direction)
    const float xsA = xbase;
    const float xsB = xbase + 13.0f * xstep;
    int eA = (int)floorf(xsA); eA = min(max(eA, 0), W - 1);
    int eB = (int)floorf(xsB); eB = min(max(eB, 0), W - 1);
    const int xmin = min(eA, eB);
    const int xmax = min(max(eA, eB) + 1, W - 1);
    const int Wd   = xmax - xmin + 1;        // 1..50

    // this thread's fixed x-tap (ix = j), window-relative
    float wx = 0.0f; bool vx = false; int c0 = 0, c1 = 0;
    if (j < CROP) {
        const float xsv = xbase + (float)j * xstep;
        vx = (xsv >= 0.0f) && (xsv <= (float)(W - 1));
        const float xfl = floorf(xsv);
        wx = xsv - xfl;
        int xi = (int)xfl; xi = min(max(xi, 0), W - 1);
        c0 = xi - xmin;
        c1 = min(xi + 1, W - 1) - xmin;
    }

    const __half* srcbase = fmh + ((long)bat * (H * W)) * C + slab * SLABCH + g * 8;

    int tag0 = -1, tag1 = -1;                // row id resident in LDS slot 0/1

    float acc[8];
    #pragma unroll
    for (int c = 0; c < 8; ++c) acc[c] = -__builtin_inff();

    for (int iy = 0; iy < CROP; ++iy) {
        const float ysv = ybase + (float)iy * ystep;
        const bool  vy  = (ysv >= 0.0f) && (ysv <= (float)(H - 1));
        const float yfl = floorf(ysv);
        const float wy  = ysv - yfl;
        int ra = (int)yfl; ra = min(max(ra, 0), H - 1);
        const int rb = min(ra + 1, H - 1);
        const int sa = ra & 1, sb = rb & 1;  // parity slots (rb=ra+1 => opposite)

        const bool needA = ((sa ? tag1 : tag0) != ra);
        const bool needB = (rb != ra) && ((sb ? tag1 : tag0) != rb);
        if (needA || needB) {                // block-uniform condition
            __syncthreads();                 // protect readers of slots
            if (needA) {
                const __half* src = srcbase + (long)(ra * W + xmin) * C;
                for (int px = j; px < Wd; px += 16)
                    *reinterpret_cast<float4*>(&lds[sa][px][g * 8]) =
                        *reinterpret_cast<const float4*>(src + (long)px * C);
            }
            if (needB) {
                const __half* src = srcbase + (long)(rb * W + xmin) * C;
                for (int px = j; px < Wd; px += 16)
                    *reinterpret_cast<float4*>(&lds[sb][px][g * 8]) =
                        *reinterpret_cast<const float4*>(src + (long)px * C);
            }
            if (sa) tag1 = ra; else tag0 = ra;
            if (sb) tag1 = rb; else tag0 = rb;
            __syncthreads();
        }

        // sample (iy, ix=j), 8 channels from LDS
        if (j < CROP) {
            const float4 ta0 = *reinterpret_cast<const float4*>(&lds[sa][c0][g * 8]);
            const float4 ta1 = *reinterpret_cast<const float4*>(&lds[sa][c1][g * 8]);
            const float4 tb0 = *reinterpret_cast<const float4*>(&lds[sb][c0][g * 8]);
            const float4 tb1 = *reinterpret_cast<const float4*>(&lds[sb][c1][g * 8]);
            const __half2* ha0 = reinterpret_cast<const __half2*>(&ta0);
            const __half2* ha1 = reinterpret_cast<const __half2*>(&ta1);
            const __half2* hb0 = reinterpret_cast<const __half2*>(&tb0);
            const __half2* hb1 = reinterpret_cast<const __half2*>(&tb1);
            const bool valid = vx && vy;
            #pragma unroll
            for (int q = 0; q < 4; ++q) {
                const float2 fa0 = __half22float2(ha0[q]);
                const float2 fa1 = __half22float2(ha1[q]);
                const float2 fb0 = __half22float2(hb0[q]);
                const float2 fb1 = __half22float2(hb1[q]);
                float vA, vB;
                {   // ref order: lerp y (rows) first, then x
                    const float r0 = fa0.x + (fb0.x - fa0.x) * wy;
                    const float r1 = fa1.x + (fb1.x - fa1.x) * wy;
                    vA = r0 + (r1 - r0) * wx;
                }
                {
                    const float r0 = fa0.y + (fb0.y - fa0.y) * wy;
                    const float r1 = fa1.y + (fb1.y - fa1.y) * wy;
                    vB = r0 + (r1 - r0) * wx;
                }
                if (!valid) { vA = 0.0f; vB = 0.0f; }
                acc[2 * q]     = fmaxf(acc[2 * q],     vA);
                acc[2 * q + 1] = fmaxf(acc[2 * q + 1], vB);
            }
        }

        // after each odd iy: fold ix pairs (shfl) and write pooled row ph
        if (iy & 1) {
            const int ph = iy >> 1;
            float m[8];
            #pragma unroll
            for (int c = 0; c < 8; ++c) {
                const float o = __shfl_xor(acc[c], 16, 64);  // partner ix = j^1
                m[c] = fmaxf(acc[c], o);
                acc[c] = -__builtin_inff();                  // reset for next ph
            }
            if (((j & 1) == 0) && j < CROP) {
                const int pw = j >> 1;
                float* op = out + ((long)(n * PIX + ph * POOLEDX + pw) * C)
                          + slab * SLABCH + g * 8;
                float4 o0, o1;
                o0.x = m[0]; o0.y = m[1]; o0.z = m[2]; o0.w = m[3];
                o1.x = m[4]; o1.y = m[5]; o1.z = m[6]; o1.w = m[7];
                *reinterpret_cast<float4*>(op)     = o0;
                *reinterpret_cast<float4*>(op + 4) = o1;
            }
        }
    }
}

extern "C" void kernel_launch(void* const* d_in, const int* in_sizes, int n_in,
                              void* d_out, int out_size, void* d_ws, size_t ws_size,
                              hipStream_t stream) {
    const float* fm   = (const float*)d_in[0];
    const float* rois = (const float*)d_in[1];
    float* out  = (float*)d_out;
    __half* fmh = (__half*)d_ws;                      // 5.12 MB << ws_size

    cvt_kernel<<<NELEM / (256 * 8), 256, 0, stream>>>(fm, fmh);   // 1250 blocks
    roi_pool_kernel<<<NROI * NSLAB, 256, 0, stream>>>(fmh, rois, out);  // 1024 blocks
}

// Round 5
// 79.792 us; speedup vs baseline: 1.2322x; 1.2322x over previous
//
#include <hip/hip_runtime.h>
#include <hip/hip_fp16.h>

// ROI pooling: crop_and_resize (bilinear, 14x14) + 2x2 max pool -> (256,7,7,512) fp32
// feature_maps: (2,50,50,512) fp32 NHWC ; rois: (2,128,4) fp32
// reference permutes [1,0,3,2] -> y1=roi[1], x1=roi[0], y2=roi[3], x2=roi[2]
//
// R5: revert to R3's barrier-free skeleton (R4's LDS staging regressed 18 us:
// barriers defeat latency hiding). Changes vs R3:
//  - packed fp16 math: v_pk_fma_f16 product-form bilinear + v_pk_max_f16 pool
//    (no per-tap half->float unpack; ~2.5x fewer VALU instrs per wave).
//    absmax was 0.03125 even in pure-fp32 R1 (harness fuzz), so fp16 math
//    noise (~0.01) stays well under the 0.0875 threshold.
//  - 256-thread blocks, 4 independent waves x 1 output pixel, no LDS ->
//    sidesteps any 16-workgroup/CU residency cap (more waves to hide ~600cyc
//    tap latency), 4x fewer dispatches. launch_bounds(256,4) caps VGPR<=128.

constexpr int H = 50, W = 50, C = 512;
constexpr int POOLEDX = 7, KSIZE = 2, CROP = 14;
constexpr int RPB = 128;
constexpr int PIX = POOLEDX * POOLEDX;     // 49
constexpr int NROI = 2 * RPB;              // 256
constexpr int NTASK = NROI * PIX;          // 12544 output pixels
constexpr int NELEM = 2 * H * W * C;       // 2,560,000 floats

typedef _Float16 h8 __attribute__((ext_vector_type(8)));

// ---------- pre-pass: fm fp32 -> fp16 into workspace ----------
__global__ __launch_bounds__(256) void cvt_kernel(
    const float* __restrict__ in, __half* __restrict__ out)
{
    const int i = (blockIdx.x * 256 + threadIdx.x) * 8;
    const float4* in4 = reinterpret_cast<const float4*>(in + i);
    const float4 a = in4[0];
    const float4 b = in4[1];
    __half h[8];
    h[0]=__float2half(a.x); h[1]=__float2half(a.y); h[2]=__float2half(a.z); h[3]=__float2half(a.w);
    h[4]=__float2half(b.x); h[5]=__float2half(b.y); h[6]=__float2half(b.z); h[7]=__float2half(b.w);
    *reinterpret_cast<float4*>(out + i) = *reinterpret_cast<const float4*>(h);
}

// ---------- main: 4 waves/block, one output pixel per wave ----------
__global__ __launch_bounds__(256, 4) void roi_pool_kernel(
    const __half* __restrict__ fmh,
    const float* __restrict__ rois,
    float* __restrict__ out)
{
    const int task = blockIdx.x * 4 + (threadIdx.x >> 6);   // 0..12543
    const int lane = threadIdx.x & 63;                      // channels 8*lane..
    const int n  = task / PIX;
    const int k  = task - n * PIX;
    const int ph = k / POOLEDX;
    const int pw = k - ph * POOLEDX;
    const int bat = n / RPB;

    const float rx1 = rois[n*4+0], ry1 = rois[n*4+1];
    const float rx2 = rois[n*4+2], ry2 = rois[n*4+3];
    const float ybase = ry1 * (float)(H - 1);
    const float xbase = rx1 * (float)(W - 1);
    const float ystep = ((ry2 - ry1) * (float)(H - 1)) / (float)(CROP - 1);
    const float xstep = ((rx2 - rx1) * (float)(W - 1)) / (float)(CROP - 1);

    // x-tap params (shared across both ky)
    int   x0i[KSIZE], x1i[KSIZE];
    float wx[KSIZE];
    bool  vx[KSIZE];
    #pragma unroll
    for (int kx = 0; kx < KSIZE; ++kx) {
        const float xs = xbase + (float)(pw * KSIZE + kx) * xstep;
        vx[kx] = (xs >= 0.0f) && (xs <= (float)(W - 1));
        const float xf = floorf(xs);
        wx[kx] = xs - xf;
        int xi = (int)xf; xi = min(max(xi, 0), W - 1);
        x0i[kx] = xi;
        x1i[kx] = min(xi + 1, W - 1);
    }

    // base pointer for this wave's 8-channel group
    const __half* base = fmh + (long)bat * (H * W) * C + lane * 8;

    h8 acc;
    #pragma unroll
    for (int c = 0; c < 8; ++c) acc[c] = (_Float16)(-60000.0f);

    #pragma unroll
    for (int ky = 0; ky < KSIZE; ++ky) {
        const float ys = ybase + (float)(ph * KSIZE + ky) * ystep;
        const bool  vy = (ys >= 0.0f) && (ys <= (float)(H - 1));
        const float yf = floorf(ys);
        const float wy = ys - yf;
        int y0 = (int)yf; y0 = min(max(y0, 0), H - 1);
        const int y1 = min(y0 + 1, H - 1);

        #pragma unroll
        for (int kx = 0; kx < KSIZE; ++kx) {
            const h8 t00 = *reinterpret_cast<const h8*>(base + (long)(y0 * W + x0i[kx]) * C);
            const h8 t01 = *reinterpret_cast<const h8*>(base + (long)(y0 * W + x1i[kx]) * C);
            const h8 t10 = *reinterpret_cast<const h8*>(base + (long)(y1 * W + x0i[kx]) * C);
            const h8 t11 = *reinterpret_cast<const h8*>(base + (long)(y1 * W + x1i[kx]) * C);

            // product-form bilinear in packed fp16
            const float wxk = wx[kx];
            const _Float16 w00 = (_Float16)((1.0f - wy) * (1.0f - wxk));
            const _Float16 w01 = (_Float16)((1.0f - wy) * wxk);
            const _Float16 w10 = (_Float16)(wy * (1.0f - wxk));
            const _Float16 w11 = (_Float16)(wy * wxk);

            h8 v = t00 * w00 + t01 * w01 + t10 * w10 + t11 * w11;

            if (!(vx[kx] && vy)) {
                #pragma unroll
                for (int c = 0; c < 8; ++c) v[c] = (_Float16)0.0f;
            }

#if __has_builtin(__builtin_elementwise_max)
            acc = __builtin_elementwise_max(acc, v);
#else
            #pragma unroll
            for (int c = 0; c < 8; ++c) acc[c] = acc[c] > v[c] ? acc[c] : v[c];
#endif
        }
    }

    // epilogue: fp16 -> fp32, two float4 stores
    float4 o0, o1;
    o0.x = (float)acc[0]; o0.y = (float)acc[1]; o0.z = (float)acc[2]; o0.w = (float)acc[3];
    o1.x = (float)acc[4]; o1.y = (float)acc[5]; o1.z = (float)acc[6]; o1.w = (float)acc[7];
    float4* out4 = reinterpret_cast<float4*>(out) + (long)task * (C / 4) + lane * 2;
    out4[0] = o0;
    out4[1] = o1;
}

extern "C" void kernel_launch(void* const* d_in, const int* in_sizes, int n_in,
                              void* d_out, int out_size, void* d_ws, size_t ws_size,
                              hipStream_t stream) {
    const float* fm   = (const float*)d_in[0];
    const float* rois = (const float*)d_in[1];
    float* out  = (float*)d_out;
    __half* fmh = (__half*)d_ws;                       // 5.12 MB << ws_size

    cvt_kernel<<<NELEM / (256 * 8), 256, 0, stream>>>(fm, fmh);     // 1250 blocks
    roi_pool_kernel<<<NTASK / 4, 256, 0, stream>>>(fmh, rois, out); // 3136 blocks
}